// Round 1
// baseline (1215.768 us; speedup 1.0000x reference)
//
#include <hip/hip_runtime.h>

#define DD 128
#define NLAYERS 3

// ---- monotonic float<->uint encoding for atomicMax on floats ----
__device__ __forceinline__ unsigned enc_f(float f) {
    unsigned b = __float_as_uint(f);
    return (b & 0x80000000u) ? ~b : (b | 0x80000000u);
}
__device__ __forceinline__ float dec_f(unsigned u) {
    return __uint_as_float((u & 0x80000000u) ? (u & 0x7fffffffu) : ~u);
}

// ---- in-degree (as float) ----
__global__ void deg_kernel(const int* __restrict__ dst, float* __restrict__ deg, int nE) {
    int e = blockIdx.x * blockDim.x + threadIdx.x;
    if (e < nE) atomicAdd(&deg[dst[e]], 1.0f);
}

// ---- edge aggregation: s[dst] += x[src], mx[dst] = max(mx[dst], x[src]) ----
// gates read on device (one-hot): skip dead aggregators entirely.
__global__ void edge_agg_kernel(const float* __restrict__ x,
                                const int* __restrict__ src,
                                const int* __restrict__ dst,
                                const float* __restrict__ z_agg_l,
                                float* __restrict__ s,
                                unsigned* __restrict__ mx,
                                int nE) {
    int gid = blockIdx.x * blockDim.x + threadIdx.x;
    int e = gid >> 7;
    if (e >= nE) return;
    int d = gid & (DD - 1);
    float za0 = z_agg_l[0], za1 = z_agg_l[1], za2 = z_agg_l[2];
    bool need_sum = (za0 != 0.0f) || (za1 != 0.0f);
    bool need_max = (za2 != 0.0f);
    int sv = src[e], dv = dst[e];
    float v = x[(size_t)sv * DD + d];
    if (need_sum) atomicAdd(&s[(size_t)dv * DD + d], v);
    if (need_max) atomicMax(&mx[(size_t)dv * DD + d], enc_f(v));
}

// ---- combine: h0 = x + za0*s + za1*s/degc + za2*mx_filled  (float4 over N*D/4) ----
__global__ void combine_kernel(const float* __restrict__ x,
                               const float* __restrict__ s,
                               const unsigned* __restrict__ mx,
                               const float* __restrict__ deg,
                               const float* __restrict__ z_agg_l,
                               float* __restrict__ h0, int n4) {
    int i = blockIdx.x * blockDim.x + threadIdx.x;
    if (i >= n4) return;
    float za0 = z_agg_l[0], za1 = z_agg_l[1], za2 = z_agg_l[2];
    int node = i >> 5;                       // 32 float4 per row of 128
    float dg = deg[node];
    float inv = 1.0f / fmaxf(dg, 1.0f);
    bool nb = (dg > 0.0f) && (za2 != 0.0f);  // guard: avoid 0*NaN from empty max
    float4 sv = ((const float4*)s)[i];
    uint4  mv = ((const uint4*)mx)[i];
    float4 xv = ((const float4*)x)[i];
    float4 r;
    float c01 = za0 + za1 * inv;             // s-term: (za0 + za1/degc) * s
    r.x = xv.x + c01 * sv.x + za2 * (nb ? dec_f(mv.x) : 0.0f);
    r.y = xv.y + c01 * sv.y + za2 * (nb ? dec_f(mv.y) : 0.0f);
    r.z = xv.z + c01 * sv.z + za2 * (nb ? dec_f(mv.z) : 0.0f);
    r.w = xv.w + c01 * sv.w + za2 * (nb ? dec_f(mv.w) : 0.0f);
    ((float4*)h0)[i] = r;
}

// ---- GEMM: out = [skip +] relu(A @ W + bias); A:[M,128], W:[128,128] k-major ----
template<bool SKIP>
__global__ __launch_bounds__(256) void gemm_kernel(const float* __restrict__ A,
                                                   const float* __restrict__ W,
                                                   const float* __restrict__ bias,
                                                   const float* skip,
                                                   float* out, int M) {
    __shared__ float As[64][DD];             // 32 KiB
    int t = threadIdx.x;
    int row0 = blockIdx.x * 64;
    const float4* Ag = (const float4*)A;
    int base4 = row0 * 32;                   // 32 float4 per row
    int limit4 = M * 32;
#pragma unroll
    for (int i = 0; i < 8; ++i) {
        int idx = t + i * 256;               // 0..2047
        float4 v;
        if (base4 + idx < limit4) v = Ag[base4 + idx];
        else v = make_float4(0.f, 0.f, 0.f, 0.f);
        ((float4*)As)[idx] = v;
    }
    __syncthreads();

    int tx = t & 31, ty = t >> 5;
    int c0 = tx * 4;
    int r0 = ty * 8;
    float4 acc[8];
#pragma unroll
    for (int i = 0; i < 8; ++i) acc[i] = make_float4(0.f, 0.f, 0.f, 0.f);

    const float4* Wv = (const float4*)W;
    for (int k = 0; k < DD; k += 4) {
        float4 w0 = Wv[(k + 0) * 32 + tx];
        float4 w1 = Wv[(k + 1) * 32 + tx];
        float4 w2 = Wv[(k + 2) * 32 + tx];
        float4 w3 = Wv[(k + 3) * 32 + tx];
#pragma unroll
        for (int i = 0; i < 8; ++i) {
            float4 a = *(const float4*)&As[r0 + i][k];
            acc[i].x += a.x * w0.x + a.y * w1.x + a.z * w2.x + a.w * w3.x;
            acc[i].y += a.x * w0.y + a.y * w1.y + a.z * w2.y + a.w * w3.y;
            acc[i].z += a.x * w0.z + a.y * w1.z + a.z * w2.z + a.w * w3.z;
            acc[i].w += a.x * w0.w + a.y * w1.w + a.z * w2.w + a.w * w3.w;
        }
    }

    float4 b4 = *(const float4*)&bias[c0];
#pragma unroll
    for (int i = 0; i < 8; ++i) {
        int r = row0 + r0 + i;
        if (r < M) {
            float4 v;
            v.x = fmaxf(acc[i].x + b4.x, 0.f);
            v.y = fmaxf(acc[i].y + b4.y, 0.f);
            v.z = fmaxf(acc[i].z + b4.z, 0.f);
            v.w = fmaxf(acc[i].w + b4.w, 0.f);
            if (SKIP) {
                float4 sk = *(const float4*)&skip[(size_t)r * DD + c0];
                v.x += sk.x; v.y += sk.y; v.z += sk.z; v.w += sk.w;
            }
            *(float4*)&out[(size_t)r * DD + c0] = v;
        }
    }
}

// ---- global pooling: one block per graph, binary-search node range ----
__global__ void pool_kernel(const float* __restrict__ x, const int* __restrict__ batch,
                            const float* __restrict__ z_pool, float* __restrict__ out,
                            int nN) {
    int b = blockIdx.x;
    int t = threadIdx.x;                     // 256
    int c = t & (DD - 1);
    int p = t >> 7;                          // 0/1

    int lo = 0, hi = nN;
    while (lo < hi) { int mid = (lo + hi) >> 1; if (batch[mid] < b) lo = mid + 1; else hi = mid; }
    int start = lo;
    hi = nN;
    while (lo < hi) { int mid = (lo + hi) >> 1; if (batch[mid] < b + 1) lo = mid + 1; else hi = mid; }
    int end = lo;

    float sum = 0.f, mv = -3.402823466e38f;
    for (int i = start + p; i < end; i += 2) {
        float v = x[(size_t)i * DD + c];
        sum += v; mv = fmaxf(mv, v);
    }
    __shared__ float ssum[256], smax[256];
    ssum[t] = sum; smax[t] = mv;
    __syncthreads();
    if (p == 0) {
        float ts = sum + ssum[t + 128];
        float tm = fmaxf(mv, smax[t + 128]);
        int cnt = end - start;
        float zp0 = z_pool[0], zp1 = z_pool[1], zp2 = z_pool[2];
        float pm = ts / fmaxf((float)cnt, 1.0f);
        float pmx = (cnt > 0) ? tm : 0.0f;
        out[(size_t)b * DD + c] = zp0 * ts + zp1 * pm + zp2 * pmx;
    }
}

extern "C" void kernel_launch(void* const* d_in, const int* in_sizes, int n_in,
                              void* d_out, int out_size, void* d_ws, size_t ws_size,
                              hipStream_t stream) {
    const float* x_in   = (const float*)d_in[0];
    const int*   eidx   = (const int*)d_in[1];
    const int*   batch  = (const int*)d_in[2];
    const float* z_agg  = (const float*)d_in[3];
    const float* z_pool = (const float*)d_in[4];
    const float* W1     = (const float*)d_in[5];
    const float* b1     = (const float*)d_in[6];
    const float* W2     = (const float*)d_in[7];
    const float* b2     = (const float*)d_in[8];

    int nN = in_sizes[0] / DD;       // 50000
    int nE = in_sizes[1] / 2;        // 600000
    int nB = out_size / DD;          // 64
    const int* src = eidx;
    const int* dst = eidx + nE;

    char* ws = (char*)d_ws;
    size_t nd = (size_t)nN * DD * sizeof(float);
    float*    x   = (float*)(ws);
    float*    h0  = (float*)(ws + nd);
    float*    s   = (float*)(ws + 2 * nd);
    unsigned* mx  = (unsigned*)(ws + 3 * nd);
    float*    h1  = (float*)mx;      // mx dead after combine; reuse as h1
    float*    deg = (float*)(ws + 4 * nd);

    hipMemcpyAsync(x, x_in, nd, hipMemcpyDeviceToDevice, stream);
    hipMemsetAsync(deg, 0, (size_t)nN * sizeof(float), stream);
    deg_kernel<<<(nE + 255) / 256, 256, 0, stream>>>(dst, deg, nE);

    int egrid = (int)(((size_t)nE * DD + 255) / 256);
    int n4 = nN * DD / 4;
    int cgrid = (n4 + 255) / 256;
    int ggrid = (nN + 63) / 64;

    for (int l = 0; l < NLAYERS; ++l) {
        hipMemsetAsync(s, 0, nd, stream);
        hipMemsetAsync(mx, 0, nd, stream);
        edge_agg_kernel<<<egrid, 256, 0, stream>>>(x, src, dst, z_agg + l * 3, s, mx, nE);
        combine_kernel<<<cgrid, 256, 0, stream>>>(x, s, mx, deg, z_agg + l * 3, h0, n4);
        gemm_kernel<false><<<ggrid, 256, 0, stream>>>(h0, W1 + (size_t)l * DD * DD,
                                                      b1 + (size_t)l * DD, nullptr, h1, nN);
        gemm_kernel<true><<<ggrid, 256, 0, stream>>>(h1, W2 + (size_t)l * DD * DD,
                                                     b2 + (size_t)l * DD, x, x, nN);
    }
    pool_kernel<<<nB, 256, 0, stream>>>(x, batch, z_pool, (float*)d_out, nN);
}

// Round 2
// 643.279 us; speedup vs baseline: 1.8900x; 1.8900x over previous
//
#include <hip/hip_runtime.h>
#include <cfloat>

#define DD 128
#define NLAYERS 3

// ================= CSR build =================

// in-degree count (int)
__global__ void deg_kernel(const int* __restrict__ dst, int* __restrict__ deg, int nE) {
    int e = blockIdx.x * blockDim.x + threadIdx.x;
    if (e < nE) atomicAdd(&deg[dst[e]], 1);
}

// single-block exclusive scan of deg -> row_ptr (nN+1 entries)
__global__ __launch_bounds__(1024) void scan_kernel(const int* __restrict__ deg,
                                                    int* __restrict__ row_ptr, int nN) {
    __shared__ int part[1024];
    int t = threadIdx.x;
    int chunk = (nN + 1023) / 1024;
    int begin = t * chunk;
    int fin = begin + chunk; if (fin > nN) fin = nN;
    int sum = 0;
    for (int i = begin; i < fin; ++i) sum += deg[i];
    part[t] = sum;
    __syncthreads();
    for (int off = 1; off < 1024; off <<= 1) {
        int other = (t >= off) ? part[t - off] : 0;
        __syncthreads();
        part[t] += other;
        __syncthreads();
    }
    int run = (t > 0) ? part[t - 1] : 0;     // exclusive prefix for this chunk
    for (int i = begin; i < fin; ++i) { row_ptr[i] = run; run += deg[i]; }
    if (t == 1023) row_ptr[nN] = part[1023];
}

// scatter edges into CSR slots (order within a node nondeterministic -> only
// affects fp-sum association, well within threshold)
__global__ void fill_kernel(const int* __restrict__ src, const int* __restrict__ dst,
                            const int* __restrict__ row_ptr, int* __restrict__ fill,
                            int* __restrict__ csr_src, int nE) {
    int e = blockIdx.x * blockDim.x + threadIdx.x;
    if (e >= nE) return;
    int d = dst[e];
    int pos = row_ptr[d] + atomicAdd(&fill[d], 1);
    csr_src[pos] = src[e];
}

// ================= fused aggregation + combine =================
// one node per 32 lanes (float4 per lane); 8 nodes per 256-thread block.
// h0 = x + (za0 + za1/degc) * sum + za2 * (deg>0 ? max : 0)
__global__ __launch_bounds__(256) void agg_combine_kernel(const float* __restrict__ x,
                                                          const int* __restrict__ csr_src,
                                                          const int* __restrict__ row_ptr,
                                                          const float* __restrict__ z_agg_l,
                                                          float* __restrict__ h0, int nN) {
    int t = threadIdx.x;
    int n = blockIdx.x * 8 + (t >> 5);
    if (n >= nN) return;
    int q = t & 31;                                   // float4 slot within row
    int start = row_ptr[n], end = row_ptr[n + 1];
    float za0 = z_agg_l[0], za1 = z_agg_l[1], za2 = z_agg_l[2];

    const float4* xv = (const float4*)x;
    float4 sum = make_float4(0.f, 0.f, 0.f, 0.f);
    float4 mx  = make_float4(-FLT_MAX, -FLT_MAX, -FLT_MAX, -FLT_MAX);
    for (int e = start; e < end; ++e) {
        int sidx = csr_src[e];
        float4 v = xv[(size_t)sidx * 32 + q];
        sum.x += v.x; sum.y += v.y; sum.z += v.z; sum.w += v.w;
        mx.x = fmaxf(mx.x, v.x); mx.y = fmaxf(mx.y, v.y);
        mx.z = fmaxf(mx.z, v.z); mx.w = fmaxf(mx.w, v.w);
    }
    int degn = end - start;
    float inv = 1.0f / fmaxf((float)degn, 1.0f);
    float c01 = za0 + za1 * inv;
    bool nb = (degn > 0);
    float4 m;
    m.x = nb ? mx.x : 0.f; m.y = nb ? mx.y : 0.f;
    m.z = nb ? mx.z : 0.f; m.w = nb ? mx.w : 0.f;
    float4 xs = xv[(size_t)n * 32 + q];
    float4 r;
    r.x = xs.x + c01 * sum.x + za2 * m.x;
    r.y = xs.y + c01 * sum.y + za2 * m.y;
    r.z = xs.z + c01 * sum.z + za2 * m.z;
    r.w = xs.w + c01 * sum.w + za2 * m.w;
    ((float4*)h0)[(size_t)n * 32 + q] = r;
}

// ================= GEMM: out = [skip +] relu(A @ W + bias) =================
template<bool SKIP>
__global__ __launch_bounds__(256) void gemm_kernel(const float* __restrict__ A,
                                                   const float* __restrict__ W,
                                                   const float* __restrict__ bias,
                                                   const float* skip,
                                                   float* out, int M) {
    __shared__ float As[64][DD];             // 32 KiB
    int t = threadIdx.x;
    int row0 = blockIdx.x * 64;
    const float4* Ag = (const float4*)A;
    int base4 = row0 * 32;
    int limit4 = M * 32;
#pragma unroll
    for (int i = 0; i < 8; ++i) {
        int idx = t + i * 256;
        float4 v;
        if (base4 + idx < limit4) v = Ag[base4 + idx];
        else v = make_float4(0.f, 0.f, 0.f, 0.f);
        ((float4*)As)[idx] = v;
    }
    __syncthreads();

    int tx = t & 31, ty = t >> 5;
    int c0 = tx * 4;
    int r0 = ty * 8;
    float4 acc[8];
#pragma unroll
    for (int i = 0; i < 8; ++i) acc[i] = make_float4(0.f, 0.f, 0.f, 0.f);

    const float4* Wv = (const float4*)W;
    for (int k = 0; k < DD; k += 4) {
        float4 w0 = Wv[(k + 0) * 32 + tx];
        float4 w1 = Wv[(k + 1) * 32 + tx];
        float4 w2 = Wv[(k + 2) * 32 + tx];
        float4 w3 = Wv[(k + 3) * 32 + tx];
#pragma unroll
        for (int i = 0; i < 8; ++i) {
            float4 a = *(const float4*)&As[r0 + i][k];
            acc[i].x += a.x * w0.x + a.y * w1.x + a.z * w2.x + a.w * w3.x;
            acc[i].y += a.x * w0.y + a.y * w1.y + a.z * w2.y + a.w * w3.y;
            acc[i].z += a.x * w0.z + a.y * w1.z + a.z * w2.z + a.w * w3.z;
            acc[i].w += a.x * w0.w + a.y * w1.w + a.z * w2.w + a.w * w3.w;
        }
    }

    float4 b4 = *(const float4*)&bias[c0];
#pragma unroll
    for (int i = 0; i < 8; ++i) {
        int r = row0 + r0 + i;
        if (r < M) {
            float4 v;
            v.x = fmaxf(acc[i].x + b4.x, 0.f);
            v.y = fmaxf(acc[i].y + b4.y, 0.f);
            v.z = fmaxf(acc[i].z + b4.z, 0.f);
            v.w = fmaxf(acc[i].w + b4.w, 0.f);
            if (SKIP) {
                float4 sk = *(const float4*)&skip[(size_t)r * DD + c0];
                v.x += sk.x; v.y += sk.y; v.z += sk.z; v.w += sk.w;
            }
            *(float4*)&out[(size_t)r * DD + c0] = v;
        }
    }
}

// ================= global pooling =================
__global__ void pool_kernel(const float* __restrict__ x, const int* __restrict__ batch,
                            const float* __restrict__ z_pool, float* __restrict__ out,
                            int nN) {
    int b = blockIdx.x;
    int t = threadIdx.x;                     // 256
    int c = t & (DD - 1);
    int p = t >> 7;                          // 0/1

    int lo = 0, hi = nN;
    while (lo < hi) { int mid = (lo + hi) >> 1; if (batch[mid] < b) lo = mid + 1; else hi = mid; }
    int start = lo;
    hi = nN;
    while (lo < hi) { int mid = (lo + hi) >> 1; if (batch[mid] < b + 1) lo = mid + 1; else hi = mid; }
    int end = lo;

    float sum = 0.f, mv = -FLT_MAX;
    for (int i = start + p; i < end; i += 2) {
        float v = x[(size_t)i * DD + c];
        sum += v; mv = fmaxf(mv, v);
    }
    __shared__ float ssum[256], smax[256];
    ssum[t] = sum; smax[t] = mv;
    __syncthreads();
    if (p == 0) {
        float ts = sum + ssum[t + 128];
        float tm = fmaxf(mv, smax[t + 128]);
        int cnt = end - start;
        float zp0 = z_pool[0], zp1 = z_pool[1], zp2 = z_pool[2];
        float pm = ts / fmaxf((float)cnt, 1.0f);
        float pmx = (cnt > 0) ? tm : 0.0f;
        out[(size_t)b * DD + c] = zp0 * ts + zp1 * pm + zp2 * pmx;
    }
}

extern "C" void kernel_launch(void* const* d_in, const int* in_sizes, int n_in,
                              void* d_out, int out_size, void* d_ws, size_t ws_size,
                              hipStream_t stream) {
    const float* x_in   = (const float*)d_in[0];
    const int*   eidx   = (const int*)d_in[1];
    const int*   batch  = (const int*)d_in[2];
    const float* z_agg  = (const float*)d_in[3];
    const float* z_pool = (const float*)d_in[4];
    const float* W1     = (const float*)d_in[5];
    const float* b1     = (const float*)d_in[6];
    const float* W2     = (const float*)d_in[7];
    const float* b2     = (const float*)d_in[8];

    int nN = in_sizes[0] / DD;       // 50000
    int nE = in_sizes[1] / 2;        // 600000
    int nB = out_size / DD;          // 64
    const int* src = eidx;
    const int* dst = eidx + nE;

    char* ws = (char*)d_ws;
    size_t nd = (size_t)nN * DD * sizeof(float);
    float* x   = (float*)(ws);
    float* h0  = (float*)(ws + nd);
    float* h1  = (float*)(ws + 2 * nd);
    int* row_ptr = (int*)(ws + 3 * nd);
    int* fill    = row_ptr + (nN + 1);
    int* deg     = fill + nN;
    int* csr_src = deg + nN;

    // ---- CSR build (once per call) ----
    hipMemsetAsync(deg, 0, (size_t)nN * sizeof(int), stream);
    hipMemsetAsync(fill, 0, (size_t)nN * sizeof(int), stream);
    deg_kernel<<<(nE + 255) / 256, 256, 0, stream>>>(dst, deg, nE);
    scan_kernel<<<1, 1024, 0, stream>>>(deg, row_ptr, nN);
    fill_kernel<<<(nE + 255) / 256, 256, 0, stream>>>(src, dst, row_ptr, fill, csr_src, nE);

    hipMemcpyAsync(x, x_in, nd, hipMemcpyDeviceToDevice, stream);

    int agrid = (nN + 7) / 8;
    int ggrid = (nN + 63) / 64;
    for (int l = 0; l < NLAYERS; ++l) {
        agg_combine_kernel<<<agrid, 256, 0, stream>>>(x, csr_src, row_ptr,
                                                      z_agg + l * 3, h0, nN);
        gemm_kernel<false><<<ggrid, 256, 0, stream>>>(h0, W1 + (size_t)l * DD * DD,
                                                      b1 + (size_t)l * DD, nullptr, h1, nN);
        gemm_kernel<true><<<ggrid, 256, 0, stream>>>(h1, W2 + (size_t)l * DD * DD,
                                                     b2 + (size_t)l * DD, x, x, nN);
    }
    pool_kernel<<<nB, 256, 0, stream>>>(x, batch, z_pool, (float*)d_out, nN);
}

// Round 3
// 573.830 us; speedup vs baseline: 2.1187x; 1.1210x over previous
//
#include <hip/hip_runtime.h>
#include <cfloat>

#define DD 128
#define NLAYERS 3
#define NPB 128   // nodes per block in pool stage A

// ---- monotonic float<->uint encoding for atomicMax on floats ----
__device__ __forceinline__ unsigned enc_f(float f) {
    unsigned b = __float_as_uint(f);
    return (b & 0x80000000u) ? ~b : (b | 0x80000000u);
}
__device__ __forceinline__ float dec_f(unsigned u) {
    return __uint_as_float((u & 0x80000000u) ? (u & 0x7fffffffu) : ~u);
}

// ================= CSR build =================

__global__ void deg_kernel(const int* __restrict__ dst, int* __restrict__ deg, int nE) {
    int e = blockIdx.x * blockDim.x + threadIdx.x;
    if (e < nE) atomicAdd(&deg[dst[e]], 1);
}

__global__ __launch_bounds__(1024) void scan_kernel(const int* __restrict__ deg,
                                                    int* __restrict__ row_ptr, int nN) {
    __shared__ int part[1024];
    int t = threadIdx.x;
    int chunk = (nN + 1023) / 1024;
    int begin = t * chunk;
    int fin = begin + chunk; if (fin > nN) fin = nN;
    int sum = 0;
    for (int i = begin; i < fin; ++i) sum += deg[i];
    part[t] = sum;
    __syncthreads();
    for (int off = 1; off < 1024; off <<= 1) {
        int other = (t >= off) ? part[t - off] : 0;
        __syncthreads();
        part[t] += other;
        __syncthreads();
    }
    int run = (t > 0) ? part[t - 1] : 0;
    for (int i = begin; i < fin; ++i) { row_ptr[i] = run; run += deg[i]; }
    if (t == 1023) row_ptr[nN] = part[1023];
}

__global__ void fill_kernel(const int* __restrict__ src, const int* __restrict__ dst,
                            const int* __restrict__ row_ptr, int* __restrict__ fill,
                            int* __restrict__ csr_src, int nE) {
    int e = blockIdx.x * blockDim.x + threadIdx.x;
    if (e >= nE) return;
    int d = dst[e];
    int pos = row_ptr[d] + atomicAdd(&fill[d], 1);
    csr_src[pos] = src[e];
}

// ================= fused aggregation + combine =================
__global__ __launch_bounds__(256) void agg_combine_kernel(const float* __restrict__ x,
                                                          const int* __restrict__ csr_src,
                                                          const int* __restrict__ row_ptr,
                                                          const float* __restrict__ z_agg_l,
                                                          float* __restrict__ h0, int nN) {
    int t = threadIdx.x;
    int n = blockIdx.x * 8 + (t >> 5);
    if (n >= nN) return;
    int q = t & 31;
    int start = row_ptr[n], end = row_ptr[n + 1];
    float za0 = z_agg_l[0], za1 = z_agg_l[1], za2 = z_agg_l[2];

    const float4* xv = (const float4*)x;
    float4 sum = make_float4(0.f, 0.f, 0.f, 0.f);
    float4 mx  = make_float4(-FLT_MAX, -FLT_MAX, -FLT_MAX, -FLT_MAX);
    for (int e = start; e < end; ++e) {
        int sidx = csr_src[e];
        float4 v = xv[(size_t)sidx * 32 + q];
        sum.x += v.x; sum.y += v.y; sum.z += v.z; sum.w += v.w;
        mx.x = fmaxf(mx.x, v.x); mx.y = fmaxf(mx.y, v.y);
        mx.z = fmaxf(mx.z, v.z); mx.w = fmaxf(mx.w, v.w);
    }
    int degn = end - start;
    float inv = 1.0f / fmaxf((float)degn, 1.0f);
    float c01 = za0 + za1 * inv;
    bool nb = (degn > 0);
    float4 m;
    m.x = nb ? mx.x : 0.f; m.y = nb ? mx.y : 0.f;
    m.z = nb ? mx.z : 0.f; m.w = nb ? mx.w : 0.f;
    float4 xs = xv[(size_t)n * 32 + q];
    float4 r;
    r.x = xs.x + c01 * sum.x + za2 * m.x;
    r.y = xs.y + c01 * sum.y + za2 * m.y;
    r.z = xs.z + c01 * sum.z + za2 * m.z;
    r.w = xs.w + c01 * sum.w + za2 * m.w;
    ((float4*)h0)[(size_t)n * 32 + q] = r;
}

// ================= GEMM: out = [skip +] relu(A @ W + bias) =================
template<bool SKIP>
__global__ __launch_bounds__(256) void gemm_kernel(const float* __restrict__ A,
                                                   const float* __restrict__ W,
                                                   const float* __restrict__ bias,
                                                   const float* skip,
                                                   float* out, int M) {
    __shared__ float As[64][DD];
    int t = threadIdx.x;
    int row0 = blockIdx.x * 64;
    const float4* Ag = (const float4*)A;
    int base4 = row0 * 32;
    int limit4 = M * 32;
#pragma unroll
    for (int i = 0; i < 8; ++i) {
        int idx = t + i * 256;
        float4 v;
        if (base4 + idx < limit4) v = Ag[base4 + idx];
        else v = make_float4(0.f, 0.f, 0.f, 0.f);
        ((float4*)As)[idx] = v;
    }
    __syncthreads();

    int tx = t & 31, ty = t >> 5;
    int c0 = tx * 4;
    int r0 = ty * 8;
    float4 acc[8];
#pragma unroll
    for (int i = 0; i < 8; ++i) acc[i] = make_float4(0.f, 0.f, 0.f, 0.f);

    const float4* Wv = (const float4*)W;
    for (int k = 0; k < DD; k += 4) {
        float4 w0 = Wv[(k + 0) * 32 + tx];
        float4 w1 = Wv[(k + 1) * 32 + tx];
        float4 w2 = Wv[(k + 2) * 32 + tx];
        float4 w3 = Wv[(k + 3) * 32 + tx];
#pragma unroll
        for (int i = 0; i < 8; ++i) {
            float4 a = *(const float4*)&As[r0 + i][k];
            acc[i].x += a.x * w0.x + a.y * w1.x + a.z * w2.x + a.w * w3.x;
            acc[i].y += a.x * w0.y + a.y * w1.y + a.z * w2.y + a.w * w3.y;
            acc[i].z += a.x * w0.z + a.y * w1.z + a.z * w2.z + a.w * w3.z;
            acc[i].w += a.x * w0.w + a.y * w1.w + a.z * w2.w + a.w * w3.w;
        }
    }

    float4 b4 = *(const float4*)&bias[c0];
#pragma unroll
    for (int i = 0; i < 8; ++i) {
        int r = row0 + r0 + i;
        if (r < M) {
            float4 v;
            v.x = fmaxf(acc[i].x + b4.x, 0.f);
            v.y = fmaxf(acc[i].y + b4.y, 0.f);
            v.z = fmaxf(acc[i].z + b4.z, 0.f);
            v.w = fmaxf(acc[i].w + b4.w, 0.f);
            if (SKIP) {
                float4 sk = *(const float4*)&skip[(size_t)r * DD + c0];
                v.x += sk.x; v.y += sk.y; v.z += sk.z; v.w += sk.w;
            }
            *(float4*)&out[(size_t)r * DD + c0] = v;
        }
    }
}

// ================= global pooling, two-stage =================
// Stage A: block owns NPB contiguous nodes; 8 row-groups (p) x 32 lanes (float4).
// Accumulate per graph-run in registers, flush to [B,D] partials on boundary.
__global__ __launch_bounds__(256) void pool_partial_kernel(const float* __restrict__ x,
                                                           const int* __restrict__ batch,
                                                           float* __restrict__ ps,
                                                           unsigned* __restrict__ pmx,
                                                           int* __restrict__ cnt, int nN) {
    int t = threadIdx.x;
    int q = t & 31;          // float4 slot within row
    int p = t >> 5;          // 0..7 row group
    int node0 = blockIdx.x * NPB;
    int nodeEnd = node0 + NPB; if (nodeEnd > nN) nodeEnd = nN;

    const float4* xv = (const float4*)x;
    float4 sum = make_float4(0.f, 0.f, 0.f, 0.f);
    float4 mx  = make_float4(-FLT_MAX, -FLT_MAX, -FLT_MAX, -FLT_MAX);
    int count = 0, g_cur = -1;

    for (int row = node0 + p; row < nodeEnd; row += 8) {
        int g = batch[row];
        if (g != g_cur) {
            if (g_cur >= 0) {
                atomicAdd(&ps[(size_t)g_cur * DD + q * 4 + 0], sum.x);
                atomicAdd(&ps[(size_t)g_cur * DD + q * 4 + 1], sum.y);
                atomicAdd(&ps[(size_t)g_cur * DD + q * 4 + 2], sum.z);
                atomicAdd(&ps[(size_t)g_cur * DD + q * 4 + 3], sum.w);
                atomicMax(&pmx[(size_t)g_cur * DD + q * 4 + 0], enc_f(mx.x));
                atomicMax(&pmx[(size_t)g_cur * DD + q * 4 + 1], enc_f(mx.y));
                atomicMax(&pmx[(size_t)g_cur * DD + q * 4 + 2], enc_f(mx.z));
                atomicMax(&pmx[(size_t)g_cur * DD + q * 4 + 3], enc_f(mx.w));
                if (q == 0) atomicAdd(&cnt[g_cur], count);
            }
            sum = make_float4(0.f, 0.f, 0.f, 0.f);
            mx  = make_float4(-FLT_MAX, -FLT_MAX, -FLT_MAX, -FLT_MAX);
            count = 0; g_cur = g;
        }
        float4 v = xv[(size_t)row * 32 + q];
        sum.x += v.x; sum.y += v.y; sum.z += v.z; sum.w += v.w;
        mx.x = fmaxf(mx.x, v.x); mx.y = fmaxf(mx.y, v.y);
        mx.z = fmaxf(mx.z, v.z); mx.w = fmaxf(mx.w, v.w);
        count++;
    }
    if (g_cur >= 0) {
        atomicAdd(&ps[(size_t)g_cur * DD + q * 4 + 0], sum.x);
        atomicAdd(&ps[(size_t)g_cur * DD + q * 4 + 1], sum.y);
        atomicAdd(&ps[(size_t)g_cur * DD + q * 4 + 2], sum.z);
        atomicAdd(&ps[(size_t)g_cur * DD + q * 4 + 3], sum.w);
        atomicMax(&pmx[(size_t)g_cur * DD + q * 4 + 0], enc_f(mx.x));
        atomicMax(&pmx[(size_t)g_cur * DD + q * 4 + 1], enc_f(mx.y));
        atomicMax(&pmx[(size_t)g_cur * DD + q * 4 + 2], enc_f(mx.z));
        atomicMax(&pmx[(size_t)g_cur * DD + q * 4 + 3], enc_f(mx.w));
        if (q == 0) atomicAdd(&cnt[g_cur], count);
    }
}

// Stage B: out = zp0*ps + zp1*ps/cnt + zp2*(cnt>0 ? dec(pmx) : 0)
__global__ void pool_final_kernel(const float* __restrict__ ps,
                                  const unsigned* __restrict__ pmx,
                                  const int* __restrict__ cnt,
                                  const float* __restrict__ z_pool,
                                  float* __restrict__ out, int total) {
    int i = blockIdx.x * blockDim.x + threadIdx.x;
    if (i >= total) return;
    int g = i >> 7;
    float zp0 = z_pool[0], zp1 = z_pool[1], zp2 = z_pool[2];
    int c = cnt[g];
    float s = ps[i];
    float pm = s / fmaxf((float)c, 1.0f);
    float pv = (c > 0) ? dec_f(pmx[i]) : 0.0f;
    out[i] = zp0 * s + zp1 * pm + zp2 * pv;
}

extern "C" void kernel_launch(void* const* d_in, const int* in_sizes, int n_in,
                              void* d_out, int out_size, void* d_ws, size_t ws_size,
                              hipStream_t stream) {
    const float* x_in   = (const float*)d_in[0];
    const int*   eidx   = (const int*)d_in[1];
    const int*   batch  = (const int*)d_in[2];
    const float* z_agg  = (const float*)d_in[3];
    const float* z_pool = (const float*)d_in[4];
    const float* W1     = (const float*)d_in[5];
    const float* b1     = (const float*)d_in[6];
    const float* W2     = (const float*)d_in[7];
    const float* b2     = (const float*)d_in[8];

    int nN = in_sizes[0] / DD;       // 50000
    int nE = in_sizes[1] / 2;        // 600000
    int nB = out_size / DD;          // 64
    const int* src = eidx;
    const int* dst = eidx + nE;

    char* ws = (char*)d_ws;
    size_t nd = (size_t)nN * DD * sizeof(float);
    float* x   = (float*)(ws);
    float* h0  = (float*)(ws + nd);
    float* h1  = (float*)(ws + 2 * nd);
    int* row_ptr = (int*)(ws + 3 * nd);
    int* fill    = row_ptr + (nN + 1);
    int* deg     = fill + nN;
    int* csr_src = deg + nN;
    float*    ps  = (float*)(csr_src + nE);
    unsigned* pmx = (unsigned*)(ps + (size_t)nB * DD);
    int*      cnt = (int*)(pmx + (size_t)nB * DD);

    // ---- CSR build (once per call) ----
    hipMemsetAsync(deg, 0, (size_t)nN * sizeof(int), stream);
    hipMemsetAsync(fill, 0, (size_t)nN * sizeof(int), stream);
    deg_kernel<<<(nE + 255) / 256, 256, 0, stream>>>(dst, deg, nE);
    scan_kernel<<<1, 1024, 0, stream>>>(deg, row_ptr, nN);
    fill_kernel<<<(nE + 255) / 256, 256, 0, stream>>>(src, dst, row_ptr, fill, csr_src, nE);

    hipMemcpyAsync(x, x_in, nd, hipMemcpyDeviceToDevice, stream);

    int agrid = (nN + 7) / 8;
    int ggrid = (nN + 63) / 64;
    for (int l = 0; l < NLAYERS; ++l) {
        agg_combine_kernel<<<agrid, 256, 0, stream>>>(x, csr_src, row_ptr,
                                                      z_agg + l * 3, h0, nN);
        gemm_kernel<false><<<ggrid, 256, 0, stream>>>(h0, W1 + (size_t)l * DD * DD,
                                                      b1 + (size_t)l * DD, nullptr, h1, nN);
        gemm_kernel<true><<<ggrid, 256, 0, stream>>>(h1, W2 + (size_t)l * DD * DD,
                                                     b2 + (size_t)l * DD, x, x, nN);
    }

    // ---- pooling ----
    hipMemsetAsync(ps, 0, (size_t)nB * DD * sizeof(float), stream);
    hipMemsetAsync(pmx, 0, (size_t)nB * DD * sizeof(unsigned), stream);  // 0 < enc(any finite)
    hipMemsetAsync(cnt, 0, (size_t)nB * sizeof(int), stream);
    pool_partial_kernel<<<(nN + NPB - 1) / NPB, 256, 0, stream>>>(x, batch, ps, pmx, cnt, nN);
    pool_final_kernel<<<(nB * DD + 255) / 256, 256, 0, stream>>>(ps, pmx, cnt, z_pool,
                                                                 (float*)d_out, nB * DD);
}

// Round 4
// 507.325 us; speedup vs baseline: 2.3964x; 1.1311x over previous
//
#include <hip/hip_runtime.h>
#include <cfloat>

#define DD 128
#define NLAYERS 3
#define NPB 128    // nodes per block in pool stage A
#define SCHUNK 1024 // elements per block in hierarchical scan

// ---- monotonic float<->uint encoding for atomicMax on floats ----
__device__ __forceinline__ unsigned enc_f(float f) {
    unsigned b = __float_as_uint(f);
    return (b & 0x80000000u) ? ~b : (b | 0x80000000u);
}
__device__ __forceinline__ float dec_f(unsigned u) {
    return __uint_as_float((u & 0x80000000u) ? (u & 0x7fffffffu) : ~u);
}

// ================= CSR build =================

__global__ void deg_kernel(const int* __restrict__ dst, int* __restrict__ deg, int nE) {
    int e = blockIdx.x * blockDim.x + threadIdx.x;
    if (e < nE) atomicAdd(&deg[dst[e]], 1);
}

// ---- hierarchical scan: sum -> top -> apply ----
__global__ __launch_bounds__(256) void scan_sum_kernel(const int* __restrict__ deg,
                                                       int* __restrict__ bsum, int nN) {
    int t = threadIdx.x;
    int base = blockIdx.x * SCHUNK + t * 4;
    int v = 0;
#pragma unroll
    for (int k = 0; k < 4; ++k) { int i = base + k; if (i < nN) v += deg[i]; }
    for (int off = 32; off; off >>= 1) v += __shfl_down(v, off, 64);
    __shared__ int wsum[4];
    if ((t & 63) == 0) wsum[t >> 6] = v;
    __syncthreads();
    if (t == 0) bsum[blockIdx.x] = wsum[0] + wsum[1] + wsum[2] + wsum[3];
}

// single small block scans block sums (G <= 256) -> exclusive boff; writes total
__global__ __launch_bounds__(256) void scan_top_kernel(const int* __restrict__ bsum,
                                                       int* __restrict__ boff,
                                                       int* __restrict__ row_ptr,
                                                       int G, int nN) {
    __shared__ int sh[256];
    int t = threadIdx.x;
    int v = (t < G) ? bsum[t] : 0;
    sh[t] = v;
    __syncthreads();
    for (int off = 1; off < 256; off <<= 1) {
        int o = (t >= off) ? sh[t - off] : 0;
        __syncthreads();
        sh[t] += o;
        __syncthreads();
    }
    if (t < G) boff[t] = sh[t] - v;           // exclusive prefix
    if (t == 255) row_ptr[nN] = sh[255];      // grand total
}

__global__ __launch_bounds__(256) void scan_apply_kernel(const int* __restrict__ deg,
                                                         const int* __restrict__ boff,
                                                         int* __restrict__ row_ptr, int nN) {
    __shared__ int sh[256];
    int t = threadIdx.x;
    int base = blockIdx.x * SCHUNK + t * 4;
    int d0 = 0, d1 = 0, d2 = 0, d3 = 0;
    if (base + 0 < nN) d0 = deg[base + 0];
    if (base + 1 < nN) d1 = deg[base + 1];
    if (base + 2 < nN) d2 = deg[base + 2];
    if (base + 3 < nN) d3 = deg[base + 3];
    int tsum = d0 + d1 + d2 + d3;
    sh[t] = tsum;
    __syncthreads();
    for (int off = 1; off < 256; off <<= 1) {
        int o = (t >= off) ? sh[t - off] : 0;
        __syncthreads();
        sh[t] += o;
        __syncthreads();
    }
    int run = boff[blockIdx.x] + sh[t] - tsum;  // exclusive base for this thread
    if (base + 0 < nN) row_ptr[base + 0] = run;           run += d0;
    if (base + 1 < nN) row_ptr[base + 1] = run;           run += d1;
    if (base + 2 < nN) row_ptr[base + 2] = run;           run += d2;
    if (base + 3 < nN) row_ptr[base + 3] = run;
}

__global__ void fill_kernel(const int* __restrict__ src, const int* __restrict__ dst,
                            const int* __restrict__ row_ptr, int* __restrict__ fill,
                            int* __restrict__ csr_src, int nE) {
    int e = blockIdx.x * blockDim.x + threadIdx.x;
    if (e >= nE) return;
    int d = dst[e];
    int pos = row_ptr[d] + atomicAdd(&fill[d], 1);
    csr_src[pos] = src[e];
}

// ================= fused aggregation + combine =================
__global__ __launch_bounds__(256) void agg_combine_kernel(const float* __restrict__ x,
                                                          const int* __restrict__ csr_src,
                                                          const int* __restrict__ row_ptr,
                                                          const float* __restrict__ z_agg_l,
                                                          float* __restrict__ h0, int nN) {
    int t = threadIdx.x;
    int n = blockIdx.x * 8 + (t >> 5);
    if (n >= nN) return;
    int q = t & 31;
    int start = row_ptr[n], end = row_ptr[n + 1];
    float za0 = z_agg_l[0], za1 = z_agg_l[1], za2 = z_agg_l[2];

    const float4* xv = (const float4*)x;
    float4 sum = make_float4(0.f, 0.f, 0.f, 0.f);
    float4 mx  = make_float4(-FLT_MAX, -FLT_MAX, -FLT_MAX, -FLT_MAX);
    for (int e = start; e < end; ++e) {
        int sidx = csr_src[e];
        float4 v = xv[(size_t)sidx * 32 + q];
        sum.x += v.x; sum.y += v.y; sum.z += v.z; sum.w += v.w;
        mx.x = fmaxf(mx.x, v.x); mx.y = fmaxf(mx.y, v.y);
        mx.z = fmaxf(mx.z, v.z); mx.w = fmaxf(mx.w, v.w);
    }
    int degn = end - start;
    float inv = 1.0f / fmaxf((float)degn, 1.0f);
    float c01 = za0 + za1 * inv;
    bool nb = (degn > 0);
    float4 m;
    m.x = nb ? mx.x : 0.f; m.y = nb ? mx.y : 0.f;
    m.z = nb ? mx.z : 0.f; m.w = nb ? mx.w : 0.f;
    float4 xs = xv[(size_t)n * 32 + q];
    float4 r;
    r.x = xs.x + c01 * sum.x + za2 * m.x;
    r.y = xs.y + c01 * sum.y + za2 * m.y;
    r.z = xs.z + c01 * sum.z + za2 * m.z;
    r.w = xs.w + c01 * sum.w + za2 * m.w;
    ((float4*)h0)[(size_t)n * 32 + q] = r;
}

// ================= GEMM: out = [skip +] relu(A @ W + bias) =================
template<bool SKIP>
__global__ __launch_bounds__(256) void gemm_kernel(const float* __restrict__ A,
                                                   const float* __restrict__ W,
                                                   const float* __restrict__ bias,
                                                   const float* skip,
                                                   float* out, int M) {
    __shared__ float As[64][DD];
    int t = threadIdx.x;
    int row0 = blockIdx.x * 64;
    const float4* Ag = (const float4*)A;
    int base4 = row0 * 32;
    int limit4 = M * 32;
#pragma unroll
    for (int i = 0; i < 8; ++i) {
        int idx = t + i * 256;
        float4 v;
        if (base4 + idx < limit4) v = Ag[base4 + idx];
        else v = make_float4(0.f, 0.f, 0.f, 0.f);
        ((float4*)As)[idx] = v;
    }
    __syncthreads();

    int tx = t & 31, ty = t >> 5;
    int c0 = tx * 4;
    int r0 = ty * 8;
    float4 acc[8];
#pragma unroll
    for (int i = 0; i < 8; ++i) acc[i] = make_float4(0.f, 0.f, 0.f, 0.f);

    const float4* Wv = (const float4*)W;
    for (int k = 0; k < DD; k += 4) {
        float4 w0 = Wv[(k + 0) * 32 + tx];
        float4 w1 = Wv[(k + 1) * 32 + tx];
        float4 w2 = Wv[(k + 2) * 32 + tx];
        float4 w3 = Wv[(k + 3) * 32 + tx];
#pragma unroll
        for (int i = 0; i < 8; ++i) {
            float4 a = *(const float4*)&As[r0 + i][k];
            acc[i].x += a.x * w0.x + a.y * w1.x + a.z * w2.x + a.w * w3.x;
            acc[i].y += a.x * w0.y + a.y * w1.y + a.z * w2.y + a.w * w3.y;
            acc[i].z += a.x * w0.z + a.y * w1.z + a.z * w2.z + a.w * w3.z;
            acc[i].w += a.x * w0.w + a.y * w1.w + a.z * w2.w + a.w * w3.w;
        }
    }

    float4 b4 = *(const float4*)&bias[c0];
#pragma unroll
    for (int i = 0; i < 8; ++i) {
        int r = row0 + r0 + i;
        if (r < M) {
            float4 v;
            v.x = fmaxf(acc[i].x + b4.x, 0.f);
            v.y = fmaxf(acc[i].y + b4.y, 0.f);
            v.z = fmaxf(acc[i].z + b4.z, 0.f);
            v.w = fmaxf(acc[i].w + b4.w, 0.f);
            if (SKIP) {
                float4 sk = *(const float4*)&skip[(size_t)r * DD + c0];
                v.x += sk.x; v.y += sk.y; v.z += sk.z; v.w += sk.w;
            }
            *(float4*)&out[(size_t)r * DD + c0] = v;
        }
    }
}

// ================= global pooling, two-stage =================
__global__ __launch_bounds__(256) void pool_partial_kernel(const float* __restrict__ x,
                                                           const int* __restrict__ batch,
                                                           float* __restrict__ ps,
                                                           unsigned* __restrict__ pmx,
                                                           int* __restrict__ cnt, int nN) {
    int t = threadIdx.x;
    int q = t & 31;
    int p = t >> 5;
    int node0 = blockIdx.x * NPB;
    int nodeEnd = node0 + NPB; if (nodeEnd > nN) nodeEnd = nN;

    const float4* xv = (const float4*)x;
    float4 sum = make_float4(0.f, 0.f, 0.f, 0.f);
    float4 mx  = make_float4(-FLT_MAX, -FLT_MAX, -FLT_MAX, -FLT_MAX);
    int count = 0, g_cur = -1;

    for (int row = node0 + p; row < nodeEnd; row += 8) {
        int g = batch[row];
        if (g != g_cur) {
            if (g_cur >= 0) {
                atomicAdd(&ps[(size_t)g_cur * DD + q * 4 + 0], sum.x);
                atomicAdd(&ps[(size_t)g_cur * DD + q * 4 + 1], sum.y);
                atomicAdd(&ps[(size_t)g_cur * DD + q * 4 + 2], sum.z);
                atomicAdd(&ps[(size_t)g_cur * DD + q * 4 + 3], sum.w);
                atomicMax(&pmx[(size_t)g_cur * DD + q * 4 + 0], enc_f(mx.x));
                atomicMax(&pmx[(size_t)g_cur * DD + q * 4 + 1], enc_f(mx.y));
                atomicMax(&pmx[(size_t)g_cur * DD + q * 4 + 2], enc_f(mx.z));
                atomicMax(&pmx[(size_t)g_cur * DD + q * 4 + 3], enc_f(mx.w));
                if (q == 0) atomicAdd(&cnt[g_cur], count);
            }
            sum = make_float4(0.f, 0.f, 0.f, 0.f);
            mx  = make_float4(-FLT_MAX, -FLT_MAX, -FLT_MAX, -FLT_MAX);
            count = 0; g_cur = g;
        }
        float4 v = xv[(size_t)row * 32 + q];
        sum.x += v.x; sum.y += v.y; sum.z += v.z; sum.w += v.w;
        mx.x = fmaxf(mx.x, v.x); mx.y = fmaxf(mx.y, v.y);
        mx.z = fmaxf(mx.z, v.z); mx.w = fmaxf(mx.w, v.w);
        count++;
    }
    if (g_cur >= 0) {
        atomicAdd(&ps[(size_t)g_cur * DD + q * 4 + 0], sum.x);
        atomicAdd(&ps[(size_t)g_cur * DD + q * 4 + 1], sum.y);
        atomicAdd(&ps[(size_t)g_cur * DD + q * 4 + 2], sum.z);
        atomicAdd(&ps[(size_t)g_cur * DD + q * 4 + 3], sum.w);
        atomicMax(&pmx[(size_t)g_cur * DD + q * 4 + 0], enc_f(mx.x));
        atomicMax(&pmx[(size_t)g_cur * DD + q * 4 + 1], enc_f(mx.y));
        atomicMax(&pmx[(size_t)g_cur * DD + q * 4 + 2], enc_f(mx.z));
        atomicMax(&pmx[(size_t)g_cur * DD + q * 4 + 3], enc_f(mx.w));
        if (q == 0) atomicAdd(&cnt[g_cur], count);
    }
}

__global__ void pool_final_kernel(const float* __restrict__ ps,
                                  const unsigned* __restrict__ pmx,
                                  const int* __restrict__ cnt,
                                  const float* __restrict__ z_pool,
                                  float* __restrict__ out, int total) {
    int i = blockIdx.x * blockDim.x + threadIdx.x;
    if (i >= total) return;
    int g = i >> 7;
    float zp0 = z_pool[0], zp1 = z_pool[1], zp2 = z_pool[2];
    int c = cnt[g];
    float s = ps[i];
    float pm = s / fmaxf((float)c, 1.0f);
    float pv = (c > 0) ? dec_f(pmx[i]) : 0.0f;
    out[i] = zp0 * s + zp1 * pm + zp2 * pv;
}

extern "C" void kernel_launch(void* const* d_in, const int* in_sizes, int n_in,
                              void* d_out, int out_size, void* d_ws, size_t ws_size,
                              hipStream_t stream) {
    const float* x_in   = (const float*)d_in[0];
    const int*   eidx   = (const int*)d_in[1];
    const int*   batch  = (const int*)d_in[2];
    const float* z_agg  = (const float*)d_in[3];
    const float* z_pool = (const float*)d_in[4];
    const float* W1     = (const float*)d_in[5];
    const float* b1     = (const float*)d_in[6];
    const float* W2     = (const float*)d_in[7];
    const float* b2     = (const float*)d_in[8];

    int nN = in_sizes[0] / DD;       // 50000
    int nE = in_sizes[1] / 2;        // 600000
    int nB = out_size / DD;          // 64
    const int* src = eidx;
    const int* dst = eidx + nE;

    char* ws = (char*)d_ws;
    size_t nd = (size_t)nN * DD * sizeof(float);
    float* x   = (float*)(ws);
    float* h0  = (float*)(ws + nd);
    float* h1  = (float*)(ws + 2 * nd);
    int* row_ptr = (int*)(ws + 3 * nd);
    int* fill    = row_ptr + (nN + 1);
    int* deg     = fill + nN;
    int* csr_src = deg + nN;
    float*    ps  = (float*)(csr_src + nE);
    unsigned* pmx = (unsigned*)(ps + (size_t)nB * DD);
    int*      cnt = (int*)(pmx + (size_t)nB * DD);
    int*      bsum = cnt + nB;
    int*      boff = bsum + 256;

    int G = (nN + SCHUNK - 1) / SCHUNK;   // 49 for nN=50000 (<=256 up to 262144 nodes)

    // ---- CSR build (once per call) ----
    hipMemsetAsync(deg, 0, (size_t)nN * sizeof(int), stream);
    hipMemsetAsync(fill, 0, (size_t)nN * sizeof(int), stream);
    deg_kernel<<<(nE + 255) / 256, 256, 0, stream>>>(dst, deg, nE);
    scan_sum_kernel<<<G, 256, 0, stream>>>(deg, bsum, nN);
    scan_top_kernel<<<1, 256, 0, stream>>>(bsum, boff, row_ptr, G, nN);
    scan_apply_kernel<<<G, 256, 0, stream>>>(deg, boff, row_ptr, nN);
    fill_kernel<<<(nE + 255) / 256, 256, 0, stream>>>(src, dst, row_ptr, fill, csr_src, nE);

    hipMemcpyAsync(x, x_in, nd, hipMemcpyDeviceToDevice, stream);

    int agrid = (nN + 7) / 8;
    int ggrid = (nN + 63) / 64;
    for (int l = 0; l < NLAYERS; ++l) {
        agg_combine_kernel<<<agrid, 256, 0, stream>>>(x, csr_src, row_ptr,
                                                      z_agg + l * 3, h0, nN);
        gemm_kernel<false><<<ggrid, 256, 0, stream>>>(h0, W1 + (size_t)l * DD * DD,
                                                      b1 + (size_t)l * DD, nullptr, h1, nN);
        gemm_kernel<true><<<ggrid, 256, 0, stream>>>(h1, W2 + (size_t)l * DD * DD,
                                                     b2 + (size_t)l * DD, x, x, nN);
    }

    // ---- pooling ----
    hipMemsetAsync(ps, 0, (size_t)nB * DD * sizeof(float), stream);
    hipMemsetAsync(pmx, 0, (size_t)nB * DD * sizeof(unsigned), stream);
    hipMemsetAsync(cnt, 0, (size_t)nB * sizeof(int), stream);
    pool_partial_kernel<<<(nN + NPB - 1) / NPB, 256, 0, stream>>>(x, batch, ps, pmx, cnt, nN);
    pool_final_kernel<<<(nB * DD + 255) / 256, 256, 0, stream>>>(ps, pmx, cnt, z_pool,
                                                                 (float*)d_out, nB * DD);
}

// Round 5
// 377.070 us; speedup vs baseline: 3.2243x; 1.3454x over previous
//
#include <hip/hip_runtime.h>
#include <cfloat>

#define DD 128
#define NLAYERS 3
#define NPB 128     // nodes per block in pool stage A
#define SCHUNK 1024 // elements per block in hierarchical scan

typedef short bf16x8 __attribute__((ext_vector_type(8)));
typedef float f32x4 __attribute__((ext_vector_type(4)));

// ---- bf16 helpers (RNE) ----
__device__ __forceinline__ unsigned short f2b(float f) {
    unsigned u = __float_as_uint(f);
    u += 0x7fffu + ((u >> 16) & 1u);
    return (unsigned short)(u >> 16);
}
__device__ __forceinline__ float b2f(unsigned short b) {
    return __uint_as_float(((unsigned)b) << 16);
}

// ---- monotonic float<->uint encoding for atomicMax on floats ----
__device__ __forceinline__ unsigned enc_f(float f) {
    unsigned b = __float_as_uint(f);
    return (b & 0x80000000u) ? ~b : (b | 0x80000000u);
}
__device__ __forceinline__ float dec_f(unsigned u) {
    return __uint_as_float((u & 0x80000000u) ? (u & 0x7fffffffu) : ~u);
}

// ================= input conversion =================

// x_in f32 -> x (f32 working copy) + xb (bf16 gather table)
__global__ void convert_x_kernel(const float* __restrict__ in, float* __restrict__ x,
                                 unsigned short* __restrict__ xb, int n4) {
    int i = blockIdx.x * blockDim.x + threadIdx.x;
    if (i >= n4) return;
    float4 v = ((const float4*)in)[i];
    ((float4*)x)[i] = v;
    ushort4 b;
    b.x = f2b(v.x); b.y = f2b(v.y); b.z = f2b(v.z); b.w = f2b(v.w);
    ((ushort4*)xb)[i] = b;
}

// W [L][128][128] f32 row-major -> bf16 swizzled into MFMA B-fragment order:
// Wb[l][(nt*4+ks)*64 + lane][j] = W[l][ks*32 + (lane>>4)*8 + j][nt*16 + (lane&15)]
__global__ void convert_w_kernel(const float* __restrict__ W, unsigned short* __restrict__ Wb,
                                 int total) {
    int idx = blockIdx.x * blockDim.x + threadIdx.x;
    if (idx >= total) return;
    int lane = idx & 63;
    int rest = idx >> 6;
    int ks = rest & 3; rest >>= 2;
    int nt = rest & 7;
    int l  = rest >> 3;
    int n = nt * 16 + (lane & 15);
    int kbase = ks * 32 + (lane >> 4) * 8;
    const float* Wl = W + (size_t)l * DD * DD;
    unsigned short* dst = Wb + (size_t)l * DD * DD + ((size_t)(nt * 4 + ks) * 64 + lane) * 8;
#pragma unroll
    for (int j = 0; j < 8; ++j) dst[j] = f2b(Wl[(size_t)(kbase + j) * DD + n]);
}

// ================= CSR build =================

__global__ void deg_kernel(const int* __restrict__ dst, int* __restrict__ deg, int nE) {
    int e = blockIdx.x * blockDim.x + threadIdx.x;
    if (e < nE) atomicAdd(&deg[dst[e]], 1);
}

__global__ __launch_bounds__(256) void scan_sum_kernel(const int* __restrict__ deg,
                                                       int* __restrict__ bsum, int nN) {
    int t = threadIdx.x;
    int base = blockIdx.x * SCHUNK + t * 4;
    int v = 0;
#pragma unroll
    for (int k = 0; k < 4; ++k) { int i = base + k; if (i < nN) v += deg[i]; }
    for (int off = 32; off; off >>= 1) v += __shfl_down(v, off, 64);
    __shared__ int wsum[4];
    if ((t & 63) == 0) wsum[t >> 6] = v;
    __syncthreads();
    if (t == 0) bsum[blockIdx.x] = wsum[0] + wsum[1] + wsum[2] + wsum[3];
}

__global__ __launch_bounds__(256) void scan_top_kernel(const int* __restrict__ bsum,
                                                       int* __restrict__ boff,
                                                       int* __restrict__ row_ptr,
                                                       int G, int nN) {
    __shared__ int sh[256];
    int t = threadIdx.x;
    int v = (t < G) ? bsum[t] : 0;
    sh[t] = v;
    __syncthreads();
    for (int off = 1; off < 256; off <<= 1) {
        int o = (t >= off) ? sh[t - off] : 0;
        __syncthreads();
        sh[t] += o;
        __syncthreads();
    }
    if (t < G) boff[t] = sh[t] - v;
    if (t == 255) row_ptr[nN] = sh[255];
}

__global__ __launch_bounds__(256) void scan_apply_kernel(const int* __restrict__ deg,
                                                         const int* __restrict__ boff,
                                                         int* __restrict__ row_ptr, int nN) {
    __shared__ int sh[256];
    int t = threadIdx.x;
    int base = blockIdx.x * SCHUNK + t * 4;
    int d0 = 0, d1 = 0, d2 = 0, d3 = 0;
    if (base + 0 < nN) d0 = deg[base + 0];
    if (base + 1 < nN) d1 = deg[base + 1];
    if (base + 2 < nN) d2 = deg[base + 2];
    if (base + 3 < nN) d3 = deg[base + 3];
    int tsum = d0 + d1 + d2 + d3;
    sh[t] = tsum;
    __syncthreads();
    for (int off = 1; off < 256; off <<= 1) {
        int o = (t >= off) ? sh[t - off] : 0;
        __syncthreads();
        sh[t] += o;
        __syncthreads();
    }
    int run = boff[blockIdx.x] + sh[t] - tsum;
    if (base + 0 < nN) row_ptr[base + 0] = run;           run += d0;
    if (base + 1 < nN) row_ptr[base + 1] = run;           run += d1;
    if (base + 2 < nN) row_ptr[base + 2] = run;           run += d2;
    if (base + 3 < nN) row_ptr[base + 3] = run;
}

__global__ void fill_kernel(const int* __restrict__ src, const int* __restrict__ dst,
                            const int* __restrict__ row_ptr, int* __restrict__ fill,
                            int* __restrict__ csr_src, int nE) {
    int e = blockIdx.x * blockDim.x + threadIdx.x;
    if (e >= nE) return;
    int d = dst[e];
    int pos = row_ptr[d] + atomicAdd(&fill[d], 1);
    csr_src[pos] = src[e];
}

// ================= fused aggregation + combine (bf16 gather, f32 accum) =================
// h0b(bf16) = x(f32) + (za0 + za1/degc) * sum + za2 * (deg>0 ? max : 0)
__global__ __launch_bounds__(256) void agg_combine_kernel(const float* __restrict__ x,
                                                          const unsigned short* __restrict__ xb,
                                                          const int* __restrict__ csr_src,
                                                          const int* __restrict__ row_ptr,
                                                          const float* __restrict__ z_agg_l,
                                                          unsigned short* __restrict__ h0b,
                                                          int nN) {
    int t = threadIdx.x;
    int n = blockIdx.x * 8 + (t >> 5);
    if (n >= nN) return;
    int q = t & 31;                      // ushort4 slot within row (4 elems)
    int start = row_ptr[n], end = row_ptr[n + 1];
    float za0 = z_agg_l[0], za1 = z_agg_l[1], za2 = z_agg_l[2];

    float4 sum = make_float4(0.f, 0.f, 0.f, 0.f);
    float4 mx  = make_float4(-FLT_MAX, -FLT_MAX, -FLT_MAX, -FLT_MAX);
    for (int e = start; e < end; ++e) {
        int sidx = csr_src[e];
        ushort4 vb = ((const ushort4*)(xb + (size_t)sidx * DD))[q];
        float vx = b2f(vb.x), vy = b2f(vb.y), vz = b2f(vb.z), vw = b2f(vb.w);
        sum.x += vx; sum.y += vy; sum.z += vz; sum.w += vw;
        mx.x = fmaxf(mx.x, vx); mx.y = fmaxf(mx.y, vy);
        mx.z = fmaxf(mx.z, vz); mx.w = fmaxf(mx.w, vw);
    }
    int degn = end - start;
    float inv = 1.0f / fmaxf((float)degn, 1.0f);
    float c01 = za0 + za1 * inv;
    bool nb = (degn > 0);
    float4 m;
    m.x = nb ? mx.x : 0.f; m.y = nb ? mx.y : 0.f;
    m.z = nb ? mx.z : 0.f; m.w = nb ? mx.w : 0.f;
    float4 xs = ((const float4*)x)[(size_t)n * 32 + q];
    ushort4 r;
    r.x = f2b(xs.x + c01 * sum.x + za2 * m.x);
    r.y = f2b(xs.y + c01 * sum.y + za2 * m.y);
    r.z = f2b(xs.z + c01 * sum.z + za2 * m.z);
    r.w = f2b(xs.w + c01 * sum.w + za2 * m.w);
    ((ushort4*)(h0b))[(size_t)n * 32 + q] = r;
}

// ================= MFMA GEMM =================
// out = relu(A@W + bias); SKIP: xo = xin + out -> xout(f32) + bout(bf16)
//       !SKIP:                       out -> bout(bf16)
// A: [M][128] bf16 row-major. Wb: swizzled fragment order (see convert_w_kernel).
// Wave computes a 16(M)x128(N) strip; block = 4 waves = 64 rows.
template<bool SKIP>
__global__ __launch_bounds__(256) void mfma_gemm_kernel(const unsigned short* __restrict__ A,
                                                        const unsigned short* __restrict__ Wb,
                                                        const float* __restrict__ bias,
                                                        const float* __restrict__ xin,
                                                        float* __restrict__ xout,
                                                        unsigned short* __restrict__ bout,
                                                        int M) {
    int t = threadIdx.x;
    int lane = t & 63;
    int wv = t >> 6;
    int row0 = blockIdx.x * 64 + wv * 16;
    int ar = row0 + (lane & 15);
    if (ar > M - 1) ar = M - 1;          // clamp loads; stores are guarded
    const unsigned short* Ap = A + (size_t)ar * DD + (lane >> 4) * 8;
    bf16x8 a0 = *(const bf16x8*)(Ap);
    bf16x8 a1 = *(const bf16x8*)(Ap + 32);
    bf16x8 a2 = *(const bf16x8*)(Ap + 64);
    bf16x8 a3 = *(const bf16x8*)(Ap + 96);

    int col = lane & 15;
    int rbase = row0 + (lane >> 4) * 4;
    const bf16x8* Wv = (const bf16x8*)Wb;
#pragma unroll
    for (int nt = 0; nt < 8; ++nt) {
        f32x4 acc = {0.f, 0.f, 0.f, 0.f};
        acc = __builtin_amdgcn_mfma_f32_16x16x32_bf16(a0, Wv[(nt * 4 + 0) * 64 + lane], acc, 0, 0, 0);
        acc = __builtin_amdgcn_mfma_f32_16x16x32_bf16(a1, Wv[(nt * 4 + 1) * 64 + lane], acc, 0, 0, 0);
        acc = __builtin_amdgcn_mfma_f32_16x16x32_bf16(a2, Wv[(nt * 4 + 2) * 64 + lane], acc, 0, 0, 0);
        acc = __builtin_amdgcn_mfma_f32_16x16x32_bf16(a3, Wv[(nt * 4 + 3) * 64 + lane], acc, 0, 0, 0);
        int c = nt * 16 + col;
        float bv = bias[c];
#pragma unroll
        for (int i = 0; i < 4; ++i) {
            int r = rbase + i;
            if (r < M) {
                float v = fmaxf(acc[i] + bv, 0.f);
                if (SKIP) {
                    float xo = xin[(size_t)r * DD + c] + v;
                    xout[(size_t)r * DD + c] = xo;
                    bout[(size_t)r * DD + c] = f2b(xo);
                } else {
                    bout[(size_t)r * DD + c] = f2b(v);
                }
            }
        }
    }
}

// ================= global pooling, two-stage (f32 x) =================
__global__ __launch_bounds__(256) void pool_partial_kernel(const float* __restrict__ x,
                                                           const int* __restrict__ batch,
                                                           float* __restrict__ ps,
                                                           unsigned* __restrict__ pmx,
                                                           int* __restrict__ cnt, int nN) {
    int t = threadIdx.x;
    int q = t & 31;
    int p = t >> 5;
    int node0 = blockIdx.x * NPB;
    int nodeEnd = node0 + NPB; if (nodeEnd > nN) nodeEnd = nN;

    const float4* xv = (const float4*)x;
    float4 sum = make_float4(0.f, 0.f, 0.f, 0.f);
    float4 mx  = make_float4(-FLT_MAX, -FLT_MAX, -FLT_MAX, -FLT_MAX);
    int count = 0, g_cur = -1;

    for (int row = node0 + p; row < nodeEnd; row += 8) {
        int g = batch[row];
        if (g != g_cur) {
            if (g_cur >= 0) {
                atomicAdd(&ps[(size_t)g_cur * DD + q * 4 + 0], sum.x);
                atomicAdd(&ps[(size_t)g_cur * DD + q * 4 + 1], sum.y);
                atomicAdd(&ps[(size_t)g_cur * DD + q * 4 + 2], sum.z);
                atomicAdd(&ps[(size_t)g_cur * DD + q * 4 + 3], sum.w);
                atomicMax(&pmx[(size_t)g_cur * DD + q * 4 + 0], enc_f(mx.x));
                atomicMax(&pmx[(size_t)g_cur * DD + q * 4 + 1], enc_f(mx.y));
                atomicMax(&pmx[(size_t)g_cur * DD + q * 4 + 2], enc_f(mx.z));
                atomicMax(&pmx[(size_t)g_cur * DD + q * 4 + 3], enc_f(mx.w));
                if (q == 0) atomicAdd(&cnt[g_cur], count);
            }
            sum = make_float4(0.f, 0.f, 0.f, 0.f);
            mx  = make_float4(-FLT_MAX, -FLT_MAX, -FLT_MAX, -FLT_MAX);
            count = 0; g_cur = g;
        }
        float4 v = xv[(size_t)row * 32 + q];
        sum.x += v.x; sum.y += v.y; sum.z += v.z; sum.w += v.w;
        mx.x = fmaxf(mx.x, v.x); mx.y = fmaxf(mx.y, v.y);
        mx.z = fmaxf(mx.z, v.z); mx.w = fmaxf(mx.w, v.w);
        count++;
    }
    if (g_cur >= 0) {
        atomicAdd(&ps[(size_t)g_cur * DD + q * 4 + 0], sum.x);
        atomicAdd(&ps[(size_t)g_cur * DD + q * 4 + 1], sum.y);
        atomicAdd(&ps[(size_t)g_cur * DD + q * 4 + 2], sum.z);
        atomicAdd(&ps[(size_t)g_cur * DD + q * 4 + 3], sum.w);
        atomicMax(&pmx[(size_t)g_cur * DD + q * 4 + 0], enc_f(mx.x));
        atomicMax(&pmx[(size_t)g_cur * DD + q * 4 + 1], enc_f(mx.y));
        atomicMax(&pmx[(size_t)g_cur * DD + q * 4 + 2], enc_f(mx.z));
        atomicMax(&pmx[(size_t)g_cur * DD + q * 4 + 3], enc_f(mx.w));
        if (q == 0) atomicAdd(&cnt[g_cur], count);
    }
}

__global__ void pool_final_kernel(const float* __restrict__ ps,
                                  const unsigned* __restrict__ pmx,
                                  const int* __restrict__ cnt,
                                  const float* __restrict__ z_pool,
                                  float* __restrict__ out, int total) {
    int i = blockIdx.x * blockDim.x + threadIdx.x;
    if (i >= total) return;
    int g = i >> 7;
    float zp0 = z_pool[0], zp1 = z_pool[1], zp2 = z_pool[2];
    int c = cnt[g];
    float s = ps[i];
    float pm = s / fmaxf((float)c, 1.0f);
    float pv = (c > 0) ? dec_f(pmx[i]) : 0.0f;
    out[i] = zp0 * s + zp1 * pm + zp2 * pv;
}

extern "C" void kernel_launch(void* const* d_in, const int* in_sizes, int n_in,
                              void* d_out, int out_size, void* d_ws, size_t ws_size,
                              hipStream_t stream) {
    const float* x_in   = (const float*)d_in[0];
    const int*   eidx   = (const int*)d_in[1];
    const int*   batch  = (const int*)d_in[2];
    const float* z_agg  = (const float*)d_in[3];
    const float* z_pool = (const float*)d_in[4];
    const float* W1     = (const float*)d_in[5];
    const float* b1     = (const float*)d_in[6];
    const float* W2     = (const float*)d_in[7];
    const float* b2     = (const float*)d_in[8];

    int nN = in_sizes[0] / DD;       // 50000
    int nE = in_sizes[1] / 2;        // 600000
    int nB = out_size / DD;          // 64
    const int* src = eidx;
    const int* dst = eidx + nE;

    char* p = (char*)d_ws;
    size_t nd = (size_t)nN * DD * sizeof(float);
    float* x            = (float*)p;           p += nd;
    unsigned short* h0b = (unsigned short*)p;  p += nd / 2;
    unsigned short* h1b = (unsigned short*)p;  p += nd / 2;
    unsigned short* xb  = (unsigned short*)p;  p += nd / 2;
    unsigned short* Wb1 = (unsigned short*)p;  p += (size_t)NLAYERS * DD * DD * 2;
    unsigned short* Wb2 = (unsigned short*)p;  p += (size_t)NLAYERS * DD * DD * 2;
    int* row_ptr = (int*)p;  p += (size_t)(nN + 1) * 4;
    int* fill    = (int*)p;  p += (size_t)nN * 4;
    int* deg     = (int*)p;  p += (size_t)nN * 4;
    int* csr_src = (int*)p;  p += (size_t)nE * 4;
    float*    ps  = (float*)p;    p += (size_t)nB * DD * 4;
    unsigned* pmx = (unsigned*)p; p += (size_t)nB * DD * 4;
    int*      cnt = (int*)p;      p += (size_t)nB * 4;
    int*      bsum = (int*)p;     p += 256 * 4;
    int*      boff = (int*)p;

    int G = (nN + SCHUNK - 1) / SCHUNK;

    // ---- conversions (once per call) ----
    int n4 = nN * DD / 4;
    convert_x_kernel<<<(n4 + 255) / 256, 256, 0, stream>>>(x_in, x, xb, n4);
    int wgroups = NLAYERS * 8 * 4 * 64;
    convert_w_kernel<<<(wgroups + 255) / 256, 256, 0, stream>>>(W1, Wb1, wgroups);
    convert_w_kernel<<<(wgroups + 255) / 256, 256, 0, stream>>>(W2, Wb2, wgroups);

    // ---- CSR build (once per call) ----
    hipMemsetAsync(deg, 0, (size_t)nN * sizeof(int), stream);
    hipMemsetAsync(fill, 0, (size_t)nN * sizeof(int), stream);
    deg_kernel<<<(nE + 255) / 256, 256, 0, stream>>>(dst, deg, nE);
    scan_sum_kernel<<<G, 256, 0, stream>>>(deg, bsum, nN);
    scan_top_kernel<<<1, 256, 0, stream>>>(bsum, boff, row_ptr, G, nN);
    scan_apply_kernel<<<G, 256, 0, stream>>>(deg, boff, row_ptr, nN);
    fill_kernel<<<(nE + 255) / 256, 256, 0, stream>>>(src, dst, row_ptr, fill, csr_src, nE);

    int agrid = (nN + 7) / 8;
    int ggrid = (nN + 63) / 64;
    for (int l = 0; l < NLAYERS; ++l) {
        agg_combine_kernel<<<agrid, 256, 0, stream>>>(x, xb, csr_src, row_ptr,
                                                      z_agg + l * 3, h0b, nN);
        mfma_gemm_kernel<false><<<ggrid, 256, 0, stream>>>(h0b, Wb1 + (size_t)l * DD * DD,
                                                           b1 + (size_t)l * DD,
                                                           nullptr, nullptr, h1b, nN);
        mfma_gemm_kernel<true><<<ggrid, 256, 0, stream>>>(h1b, Wb2 + (size_t)l * DD * DD,
                                                          b2 + (size_t)l * DD,
                                                          x, x, xb, nN);
    }

    // ---- pooling ----
    hipMemsetAsync(ps, 0, (size_t)nB * DD * sizeof(float), stream);
    hipMemsetAsync(pmx, 0, (size_t)nB * DD * sizeof(unsigned), stream);
    hipMemsetAsync(cnt, 0, (size_t)nB * sizeof(int), stream);
    pool_partial_kernel<<<(nN + NPB - 1) / NPB, 256, 0, stream>>>(x, batch, ps, pmx, cnt, nN);
    pool_final_kernel<<<(nB * DD + 255) / 256, 256, 0, stream>>>(ps, pmx, cnt, z_pool,
                                                                 (float*)d_out, nB * DD);
}